// Round 1
// baseline (265.233 us; speedup 1.0000x reference)
//
#include <hip/hip_runtime.h>
#include <math.h>

// DifferentiableSoftmaxTree: hierarchical (binary-tree) softmax NLL.
// BATCH=4096, FDIM=512, DEPTH=16, NUM_INTERNAL=49999.
// One 64-lane wave per batch element; lane i owns feature dims
// {4i..4i+3} and {256+4i..256+4i+3}. node_weights layout is
// [node][d][c] (c in {0,1}) so each lane reads 2x float4 per 256-dim
// chunk -> fully coalesced dwordx4. Next node's weights are prefetched
// (double-buffered in registers) across the shuffle-reduce chain.

constexpr int BATCH = 4096;
constexpr int FDIM  = 512;
constexpr int DEPTH = 16;

__global__ __launch_bounds__(256) void hstree_loss(
    const float* __restrict__ features,
    const int*   __restrict__ targets,
    const float* __restrict__ node_weights,
    const int*   __restrict__ path_nodes,
    const int*   __restrict__ path_dirs,
    float*       __restrict__ out)
{
    const int lane = threadIdx.x & 63;
    const int b    = (blockIdx.x << 2) + (threadIdx.x >> 6);
    if (b >= BATCH) return;

    // target is wave-uniform -> force into SGPR so path-map loads go scalar
    const int t = __builtin_amdgcn_readfirstlane(targets[b]);

    int nodes[DEPTH];
    int dirs[DEPTH];
#pragma unroll
    for (int k = 0; k < DEPTH; ++k) {
        nodes[k] = path_nodes[t * DEPTH + k];
        dirs[k]  = path_dirs [t * DEPTH + k];
    }

    // features: two float4 per lane
    const float4* fb = (const float4*)(features + (size_t)b * FDIM);
    const float4 f0 = fb[lane];        // dims 4*lane .. 4*lane+3
    const float4 f1 = fb[lane + 64];   // dims 256+4*lane .. 256+4*lane+3

    // weight base pointer for path step k (clamped: padding (-1) -> node 0,
    // masked out later; node 0 is L2-hot so the wasted load is ~free)
    auto wbase = [&](int k) -> const float4* {
        int n = nodes[k] < 0 ? 0 : nodes[k];
        return (const float4*)(node_weights + (size_t)n * (FDIM * 2));
    };

    // prefetch k=0
    const float4* wp = wbase(0);
    float4 a0 = wp[2 * lane];
    float4 a1 = wp[2 * lane + 1];
    float4 a2 = wp[128 + 2 * lane];
    float4 a3 = wp[128 + 2 * lane + 1];

    float loss = 0.0f;

#pragma unroll 1
    for (int k = 0; k < DEPTH; ++k) {
        // issue next node's loads before the dependent reduce chain
        const int kn = (k + 1 < DEPTH) ? (k + 1) : k;
        const float4* np = wbase(kn);
        float4 b0 = np[2 * lane];
        float4 b1 = np[2 * lane + 1];
        float4 b2 = np[128 + 2 * lane];
        float4 b3 = np[128 + 2 * lane + 1];

        // partial dots: a0 = (w[d][0],w[d][1],w[d+1][0],w[d+1][1]) etc.
        float l0 = f0.x * a0.x + f0.y * a0.z + f0.z * a1.x + f0.w * a1.z
                 + f1.x * a2.x + f1.y * a2.z + f1.z * a3.x + f1.w * a3.z;
        float l1 = f0.x * a0.y + f0.y * a0.w + f0.z * a1.y + f0.w * a1.w
                 + f1.x * a2.y + f1.y * a2.w + f1.z * a3.y + f1.w * a3.w;

        // wave-64 butterfly reduction of both logits
#pragma unroll
        for (int off = 32; off; off >>= 1) {
            l0 += __shfl_xor(l0, off, 64);
            l1 += __shfl_xor(l1, off, 64);
        }

        if (nodes[k] >= 0) {
            // -log_softmax(l)[dir] == softplus(-(l_dir - l_other)), stable form
            const float z = (dirs[k] == 0) ? (l0 - l1) : (l1 - l0);
            loss += fmaxf(-z, 0.0f) + log1pf(__expf(-fabsf(z)));
        }

        a0 = b0; a1 = b1; a2 = b2; a3 = b3;
    }

    if (lane == 0) out[b] = loss;
}

extern "C" void kernel_launch(void* const* d_in, const int* in_sizes, int n_in,
                              void* d_out, int out_size, void* d_ws, size_t ws_size,
                              hipStream_t stream) {
    const float* features     = (const float*)d_in[0];
    const int*   targets      = (const int*)  d_in[1];
    const float* node_weights = (const float*)d_in[2];
    const int*   path_nodes   = (const int*)  d_in[3];
    const int*   path_dirs    = (const int*)  d_in[4];
    float*       out          = (float*)d_out;

    // 4 waves (4 batch rows) per 256-thread block
    hstree_loss<<<BATCH / 4, 256, 0, stream>>>(
        features, targets, node_weights, path_nodes, path_dirs, out);
}